// Round 1
// baseline (212.801 us; speedup 1.0000x reference)
//
#include <hip/hip_runtime.h>

#define NROWS 4096
#define DCOLS 4096
#define MARGIN 1.2f

// One block per row: loss_i = y_i * d2 + (1-y_i) * max(0, MARGIN - sqrt(d2)),
// d2 = sum_j (x0[i][j] - x1[i][j])^2
__global__ __launch_bounds__(256) void row_loss_kernel(
    const float* __restrict__ x0, const float* __restrict__ x1,
    const int* __restrict__ y, float* __restrict__ row_out) {
    const int row = blockIdx.x;
    const float4* __restrict__ a = (const float4*)(x0 + (size_t)row * DCOLS);
    const float4* __restrict__ b = (const float4*)(x1 + (size_t)row * DCOLS);

    float s = 0.f;
    // DCOLS/4 = 1024 float4 per row, 256 threads -> 4 iterations each, coalesced.
    #pragma unroll 4
    for (int i = threadIdx.x; i < DCOLS / 4; i += 256) {
        float4 va = a[i];
        float4 vb = b[i];
        float dx = va.x - vb.x;
        float dy = va.y - vb.y;
        float dz = va.z - vb.z;
        float dw = va.w - vb.w;
        s = fmaf(dx, dx, s);
        s = fmaf(dy, dy, s);
        s = fmaf(dz, dz, s);
        s = fmaf(dw, dw, s);
    }

    // wave64 reduction
    #pragma unroll
    for (int off = 32; off > 0; off >>= 1) s += __shfl_down(s, off, 64);

    __shared__ float smem[4];
    const int lane = threadIdx.x & 63;
    const int wid = threadIdx.x >> 6;
    if (lane == 0) smem[wid] = s;
    __syncthreads();

    if (threadIdx.x == 0) {
        float d2 = smem[0] + smem[1] + smem[2] + smem[3];
        float d = sqrtf(d2);
        float clamped = fmaxf(MARGIN - d, 0.f);
        float yf = (float)y[row];
        row_out[row] = yf * d2 + (1.f - yf) * clamped;
    }
}

__global__ __launch_bounds__(256) void final_reduce_kernel(
    const float* __restrict__ row_out, float* __restrict__ out) {
    float s = 0.f;
    for (int i = threadIdx.x; i < NROWS; i += 256) s += row_out[i];

    #pragma unroll
    for (int off = 32; off > 0; off >>= 1) s += __shfl_down(s, off, 64);

    __shared__ float smem[4];
    const int lane = threadIdx.x & 63;
    const int wid = threadIdx.x >> 6;
    if (lane == 0) smem[wid] = s;
    __syncthreads();

    if (threadIdx.x == 0) {
        out[0] = (smem[0] + smem[1] + smem[2] + smem[3]) * (1.f / (2.f * (float)NROWS));
    }
}

extern "C" void kernel_launch(void* const* d_in, const int* in_sizes, int n_in,
                              void* d_out, int out_size, void* d_ws, size_t ws_size,
                              hipStream_t stream) {
    const float* x0 = (const float*)d_in[0];
    const float* x1 = (const float*)d_in[1];
    // d_in[2], d_in[3] (x_c_0, x_c_1) are dead in the reference computation.
    const int* y = (const int*)d_in[4];

    float* row_out = (float*)d_ws;  // 4096 floats = 16 KiB scratch
    float* out = (float*)d_out;

    row_loss_kernel<<<NROWS, 256, 0, stream>>>(x0, x1, y, row_out);
    final_reduce_kernel<<<1, 256, 0, stream>>>(row_out, out);
}